// Round 5
// baseline (1676.538 us; speedup 1.0000x reference)
//
#include <hip/hip_runtime.h>
#include <math.h>

// HE color normalization: NMF (100 mult-update iters) + 0.99-quantile + recompose.
// Single persistent kernel; V, Wc, Hd, Gram all register-resident.
// R4: flat fence-free exchange with (a) poll+gather fusion (per-thread line
// ownership, copy-to-LDS on flag arrival overlaps straggler skew), (b) redundant
// per-thread Hd/Gram update (no LDS ping-pong, no extra syncthreads).

#define N_PIX (1024*1024)
#define NB    256            // blocks (1 per CU, co-resident)
#define BS    512            // threads/block (8 waves)
#define NWAVE (BS/64)
#define TT    (NB*BS)
#define PPT   (N_PIX/TT)     // 8 pixels per thread
#define NIT   100
#define EPSI  1e-8f
#define NBINS 2048
#define LSTR  32             // dwords per global line (128B)
#define LPAD  24             // LDS line stride (dwords)

// ---- workspace layout (dword offsets) ----
#define OFF_LINES 0                    // [NB][2][LSTR]: floats 0..21 payload, u32 [31] epoch
#define OFF_GH0   (NB*2*LSTR)
#define OFF_GH1   (OFF_GH0 + NBINS)
#define WS_DWORDS (OFF_GH1 + NBINS)
#define WS_BYTES  (WS_DWORDS*4)

__device__ __forceinline__ unsigned ld_rlx_u(const unsigned* p) {
    return __hip_atomic_load(p, __ATOMIC_RELAXED, __HIP_MEMORY_SCOPE_AGENT);
}
__device__ __forceinline__ float ld_rlx_f(const float* p) {
    return __hip_atomic_load(p, __ATOMIC_RELAXED, __HIP_MEMORY_SCOPE_AGENT);
}
__device__ __forceinline__ void st_rlx_f(float* p, float v) {
    __hip_atomic_store(p, v, __ATOMIC_RELAXED, __HIP_MEMORY_SCOPE_AGENT);
}
__device__ __forceinline__ void st_rlx_u(unsigned* p, unsigned v) {
    __hip_atomic_store(p, v, __ATOMIC_RELAXED, __HIP_MEMORY_SCOPE_AGENT);
}

__global__ __launch_bounds__(BS)
void he_norm_kernel(const float* __restrict__ pic,      // (3,N)
                    const float* __restrict__ Wt,       // (3,4)
                    const float* __restrict__ HtRM,     // scalar
                    const float* __restrict__ W0,       // (N,4)
                    const float* __restrict__ H0,       // (3,4)
                    float* __restrict__ out,            // (3,N)
                    unsigned char* __restrict__ ws)
{
    const int tid  = threadIdx.x;
    const int blk  = blockIdx.x;
    const int g    = blk*BS + tid;
    const int wave = tid >> 6;
    const int lane = tid & 63;

    unsigned* U = (unsigned*)ws;
    float*    F = (float*)ws;
    unsigned* gh0 = U + OFF_GH0;
    unsigned* gh1 = U + OFF_GH1;

    __shared__ float sLines[NB*LPAD];     // gathered payloads (24 KB)
    __shared__ float sS[22], sWt[12], sScal[2];
    __shared__ float sRed[NWAVE][24];
    __shared__ float sPr[16][22];
    __shared__ unsigned sHist[NBINS];
    __shared__ unsigned sSeg[256];
    __shared__ int      sBstar;
    __shared__ unsigned sCumB;

    // ---- setup: Wt to LDS; Hd, Gram into registers (identical per thread) ----
    if (tid < 12) sWt[tid] = Wt[tid];
    float hd[12], gg[16];
    #pragma unroll
    for (int j = 0; j < 12; j++) hd[j] = H0[j];
    #pragma unroll
    for (int j = 0; j < 16; j++) {
        int s_ = j >> 2, r_ = j & 3;
        gg[j] = hd[s_]*hd[r_] + hd[4+s_]*hd[4+r_] + hd[8+s_]*hd[8+r_];
    }

    // ---- persistent registers: V (optical density) and Wc ----
    float v0[PPT], v1[PPT], v2[PPT];
    float w[PPT][4];
    #pragma unroll
    for (int k = 0; k < PPT; k++) {
        int i = g + k*TT;
        float4 wv = ((const float4*)W0)[i];
        w[k][0]=wv.x; w[k][1]=wv.y; w[k][2]=wv.z; w[k][3]=wv.w;
        v0[k] = -logf(fminf(fmaxf(pic[i],           0.01f), 0.99f));
        v1[k] = -logf(fminf(fmaxf(pic[N_PIX  + i],  0.01f), 0.99f));
        v2[k] = -logf(fminf(fmaxf(pic[2*N_PIX + i], 0.01f), 0.99f));
    }
    __syncthreads();   // sWt ready

    // ---- NMF multiplicative updates ----
    for (int t = 0; t < NIT; ++t) {
        float acc[22];
        #pragma unroll
        for (int j = 0; j < 22; j++) acc[j] = 0.f;

        #pragma unroll
        for (int k = 0; k < PPT; k++) {
            float wn[4];
            #pragma unroll
            for (int r = 0; r < 4; r++) {
                float num = v0[k]*hd[r] + v1[k]*hd[4+r] + v2[k]*hd[8+r];
                float den = w[k][0]*gg[r] + w[k][1]*gg[4+r]
                          + w[k][2]*gg[8+r] + w[k][3]*gg[12+r] + EPSI;
                float rc = __builtin_amdgcn_rcpf(den);
                rc = rc * (2.0f - den*rc);          // 1 NR step: ~exact
                wn[r] = w[k][r] * num * rc;
            }
            #pragma unroll
            for (int r = 0; r < 4; r++) {
                acc[r]    += v0[k]*wn[r];
                acc[4+r]  += v1[k]*wn[r];
                acc[8+r]  += v2[k]*wn[r];
            }
            acc[12]+=wn[0]*wn[0]; acc[13]+=wn[0]*wn[1]; acc[14]+=wn[0]*wn[2]; acc[15]+=wn[0]*wn[3];
            acc[16]+=wn[1]*wn[1]; acc[17]+=wn[1]*wn[2]; acc[18]+=wn[1]*wn[3];
            acc[19]+=wn[2]*wn[2]; acc[20]+=wn[2]*wn[3]; acc[21]+=wn[3]*wn[3];
            w[k][0]=wn[0]; w[k][1]=wn[1]; w[k][2]=wn[2]; w[k][3]=wn[3];
        }

        if (t == NIT-1) break;   // last Hd update is dead code (output uses Wc only)
        const unsigned ep  = (unsigned)(t + 1);
        const int      par = (int)(ep & 1u);

        // ---- block reduce 22 accumulators (wave butterfly -> LDS) ----
        #pragma unroll
        for (int j = 0; j < 22; j++) {
            float v = acc[j];
            #pragma unroll
            for (int off = 32; off > 0; off >>= 1) v += __shfl_down(v, off, 64);
            if (lane == 0) sRed[wave][j] = v;
        }
        __syncthreads();

        // ---- publish: payload then flag, ordered by in-wave s_waitcnt ----
        if (wave == 0) {
            if (tid < 22) {
                float pa = 0.f;
                #pragma unroll
                for (int wv2 = 0; wv2 < NWAVE; wv2++) pa += sRed[wv2][tid];
                st_rlx_f(&F[(blk*2 + par)*LSTR + tid], pa);
            }
            __builtin_amdgcn_s_waitcnt(0);          // payload acked at coherence point
            if (tid == 0) st_rlx_u(&U[(blk*2 + par)*LSTR + 31], ep);
        }

        // ---- fused poll+gather: thread t owns line t, copies on arrival ----
        if (tid < NB) {
            const unsigned* p = &U[(tid*2 + par)*LSTR + 31];
            while (ld_rlx_u(p) < ep) __builtin_amdgcn_s_sleep(1);
            const float* src = &F[(tid*2 + par)*LSTR];
            float tmp[22];
            #pragma unroll
            for (int j = 0; j < 22; j++) tmp[j] = ld_rlx_f(&src[j]);
            #pragma unroll
            for (int j = 0; j < 22; j++) sLines[tid*LPAD + j] = tmp[j];
        }
        __syncthreads();

        // ---- fixed-order LDS reduction: 16 segs x 22 accs, then 16-way ----
        if (tid < 352) {
            int seg = tid / 22, j = tid - seg*22;
            float s = 0.f;
            #pragma unroll
            for (int b2 = 0; b2 < 16; b2++)
                s += sLines[(seg*16 + b2)*LPAD + j];
            sPr[seg][j] = s;
        }
        __syncthreads();
        if (tid < 22) {
            float s = 0.f;
            #pragma unroll
            for (int sg = 0; sg < 16; sg++) s += sPr[sg][tid];
            sS[tid] = s;
        }
        __syncthreads();

        // ---- Hd + Gram update: redundant per-thread, register-only ----
        {
            float nhd[12];
            const int base[4] = {12, 16, 19, 21};
            #pragma unroll
            for (int c = 0; c < 3; c++)
                #pragma unroll
                for (int r = 0; r < 4; r++) {
                    float den = EPSI;
                    #pragma unroll
                    for (int s2 = 0; s2 < 4; s2++) {
                        int lo = (s2 < r) ? s2 : r, hi = (s2 < r) ? r : s2;
                        den += hd[c*4 + s2] * sS[base[lo] + (hi - lo)];
                    }
                    nhd[c*4+r] = hd[c*4+r] * sS[c*4+r] / den;
                }
            #pragma unroll
            for (int j = 0; j < 12; j++) hd[j] = nhd[j];
            #pragma unroll
            for (int j = 0; j < 16; j++) {
                int s_ = j >> 2, r_ = j & 3;
                gg[j] = hd[s_]*hd[r_] + hd[4+s_]*hd[4+r_] + hd[8+s_]*hd[8+r_];
            }
        }
    }

    // ================= tail: quantile + recompose =================
    // ---- ep=100 (par 0): global max of Wc ----
    {
        float m = 0.f;
        #pragma unroll
        for (int k = 0; k < PPT; k++)
            #pragma unroll
            for (int r = 0; r < 4; r++) m = fmaxf(m, w[k][r]);
        #pragma unroll
        for (int off = 32; off > 0; off >>= 1) m = fmaxf(m, __shfl_down(m, off, 64));
        if (lane == 0) sRed[wave][0] = m;
        __syncthreads();
        const unsigned ep = 100u; const int par = 0;
        if (tid == 0) {
            float mm = 0.f;
            for (int wv2 = 0; wv2 < NWAVE; wv2++) mm = fmaxf(mm, sRed[wv2][0]);
            st_rlx_f(&F[(blk*2 + par)*LSTR], mm);
            __builtin_amdgcn_s_waitcnt(0);
            st_rlx_u(&U[(blk*2 + par)*LSTR + 31], ep);
        }
        if (tid < NB) {
            const unsigned* p = &U[(tid*2 + par)*LSTR + 31];
            while (ld_rlx_u(p) < ep) __builtin_amdgcn_s_sleep(1);
            sLines[tid*LPAD] = ld_rlx_f(&F[(tid*2 + par)*LSTR]);
        }
        __syncthreads();
        if (tid < NB) {
            float mv = sLines[tid*LPAD];
            #pragma unroll
            for (int off = 32; off > 0; off >>= 1) mv = fmaxf(mv, __shfl_down(mv, off, 64));
            if (lane == 0) sRed[wave][1] = mv;
        }
        __syncthreads();
        if (tid == 0) {
            float mm = 0.f;
            for (int wv2 = 0; wv2 < 4; wv2++) mm = fmaxf(mm, sRed[wv2][1]);
            sScal[0] = mm * 1.0000002f;
        }
        __syncthreads();
    }
    const float gmax   = sScal[0];
    const float scale0 = (float)NBINS / gmax;

    // ---- ep=101 (par 1): histogram level 0 ----
    for (int i = tid; i < NBINS; i += BS) sHist[i] = 0u;
    __syncthreads();
    #pragma unroll
    for (int k = 0; k < PPT; k++)
        #pragma unroll
        for (int r = 0; r < 4; r++) {
            int b = (int)(w[k][r] * scale0);
            b = min(b, NBINS - 1);
            atomicAdd(&sHist[b], 1u);
        }
    __syncthreads();
    for (int i = tid; i < NBINS; i += BS) if (sHist[i]) atomicAdd(&gh0[i], sHist[i]);
    __builtin_amdgcn_s_waitcnt(0);      // every wave: its hist atomics acked
    __syncthreads();
    if (tid == 0) st_rlx_u(&U[(blk*2 + 1)*LSTR + 31], 101u);
    if (tid < NB) {
        const unsigned* p = &U[(tid*2 + 1)*LSTR + 31];
        while (ld_rlx_u(p) < 101u) __builtin_amdgcn_s_sleep(1);
    }
    __syncthreads();

    // ---- scan level 0 (redundant in every block, exact integer counts) ----
    const double kfd = 0.99 * (double)(4*N_PIX - 1);   // fractional rank
    if (tid < 256) {
        unsigned s2 = 0;
        for (int i = 0; i < 8; i++) s2 += ld_rlx_u(&gh0[tid*8 + i]);
        sSeg[tid] = s2;
    }
    __syncthreads();
    if (tid == 0) {
        unsigned cum = 0; int seg = 0;
        for (int i2 = 0; i2 < 256; i2++) {
            if ((double)(cum + sSeg[i2]) > kfd) { seg = i2; break; }
            cum += sSeg[i2];
        }
        unsigned c2 = cum; int b = seg*8;
        for (int i2 = 0; i2 < 8; i2++) {
            unsigned h = ld_rlx_u(&gh0[seg*8 + i2]);
            if ((double)(c2 + h) > kfd) { b = seg*8 + i2; break; }
            c2 += h;
        }
        sBstar = b; sCumB = c2;
    }
    __syncthreads();
    const int   bstar  = sBstar;
    const float lo1    = (float)bstar / scale0;
    const float scale1 = scale0 * (float)NBINS;

    // ---- ep=102 (par 0): histogram level 1 (values inside bin bstar only) ----
    for (int i = tid; i < NBINS; i += BS) sHist[i] = 0u;
    __syncthreads();
    #pragma unroll
    for (int k = 0; k < PPT; k++)
        #pragma unroll
        for (int r = 0; r < 4; r++) {
            int b0 = min((int)(w[k][r] * scale0), NBINS - 1);
            if (b0 == bstar) {
                int b1 = (int)((w[k][r] - lo1) * scale1);
                b1 = max(0, min(b1, NBINS - 1));
                atomicAdd(&sHist[b1], 1u);
            }
        }
    __syncthreads();
    for (int i = tid; i < NBINS; i += BS) if (sHist[i]) atomicAdd(&gh1[i], sHist[i]);
    __builtin_amdgcn_s_waitcnt(0);
    __syncthreads();
    if (tid == 0) st_rlx_u(&U[(blk*2 + 0)*LSTR + 31], 102u);
    if (tid < NB) {
        const unsigned* p = &U[(tid*2 + 0)*LSTR + 31];
        while (ld_rlx_u(p) < 102u) __builtin_amdgcn_s_sleep(1);
    }
    __syncthreads();

    // ---- scan level 1 -> quantile -> scale factor (redundant) ----
    if (tid < 256) {
        unsigned s2 = 0;
        for (int i = 0; i < 8; i++) s2 += ld_rlx_u(&gh1[tid*8 + i]);
        sSeg[tid] = s2;
    }
    __syncthreads();
    if (tid == 0) {
        double jf = kfd - (double)sCumB;
        unsigned cum = 0; int seg = 0;
        for (int i2 = 0; i2 < 256; i2++) {
            if ((double)(cum + sSeg[i2]) > jf) { seg = i2; break; }
            cum += sSeg[i2];
        }
        unsigned c3 = cum; int bb = seg*8; unsigned hh = 1;
        for (int i2 = 0; i2 < 8; i2++) {
            unsigned h = ld_rlx_u(&gh1[seg*8 + i2]);
            if ((double)(c3 + h) > jf) { bb = seg*8 + i2; hh = h; break; }
            c3 += h;
        }
        double frac = (jf - (double)c3 + 0.5) / (double)hh;
        frac = fmin(fmax(frac, 0.0), 1.0);
        double q = (double)lo1 + ((double)bb + frac) / (double)scale1;
        sScal[1] = (float)((double)HtRM[0] / q);
    }
    __syncthreads();
    const float sc = sScal[1];

    // ---- recompose: out = clip(exp(-(Wt @ (Wc^T * sc))), 0, 1) ----
    #pragma unroll
    for (int k = 0; k < PPT; k++) {
        int i = g + k*TT;
        #pragma unroll
        for (int c = 0; c < 3; c++) {
            float d = sWt[c*4+0]*w[k][0] + sWt[c*4+1]*w[k][1]
                    + sWt[c*4+2]*w[k][2] + sWt[c*4+3]*w[k][3];
            float e = expf(-d * sc);
            out[c*N_PIX + i] = fminf(fmaxf(e, 0.f), 1.f);
        }
    }
}

extern "C" void kernel_launch(void* const* d_in, const int* in_sizes, int n_in,
                              void* d_out, int out_size, void* d_ws, size_t ws_size,
                              hipStream_t stream) {
    const float* pic  = (const float*)d_in[0];
    const float* Wt   = (const float*)d_in[1];
    const float* HtRM = (const float*)d_in[2];
    const float* W0   = (const float*)d_in[3];
    const float* H0   = (const float*)d_in[4];
    float* out = (float*)d_out;

    // zero epoch lines + histograms
    hipMemsetAsync(d_ws, 0, WS_BYTES, stream);
    he_norm_kernel<<<dim3(NB), dim3(BS), 0, stream>>>(
        pic, Wt, HtRM, W0, H0, out, (unsigned char*)d_ws);
}

// Round 6
// 1155.397 us; speedup vs baseline: 1.4510x; 1.4510x over previous
//
#include <hip/hip_runtime.h>
#include <math.h>

// HE color normalization: NMF (100 mult-update iters) + 0.99-quantile + recompose.
// Single persistent kernel; V, Wc, Hd, Gram register-resident.
// R5: hierarchical fence-free exchange. Level 1: each block publishes 22 partials
// + epoch flag to a private 128B line (relaxed agent stores + s_waitcnt ordering).
// Level 2: 16 group leaders gather their 16 lines (coalesced), publish group
// partials. All blocks then poll only 16 group flags and gather 16x22 coalesced.
// Reduction tree identical to R3 -> bitwise-identical results. No RMW, no fences.

#define N_PIX (1024*1024)
#define NB    256            // blocks (1 per CU, co-resident)
#define BS    512            // threads/block (8 waves)
#define NWAVE (BS/64)
#define TT    (NB*BS)
#define PPT   (N_PIX/TT)     // 8 pixels per thread
#define NIT   100
#define EPSI  1e-8f
#define NBINS 2048
#define LSTR  32             // dwords per line (128B)
#define NGRP  16

// ---- workspace layout (dword offsets) ----
#define OFF_LINES  0                        // [NB][2][LSTR]
#define OFF_GLINES (NB*2*LSTR)              // [NGRP][2][LSTR]
#define OFF_GH0    (OFF_GLINES + NGRP*2*LSTR)
#define OFF_GH1    (OFF_GH0 + NBINS)
#define WS_DWORDS  (OFF_GH1 + NBINS)
#define WS_BYTES   (WS_DWORDS*4)

__device__ __forceinline__ unsigned ld_rlx_u(const unsigned* p) {
    return __hip_atomic_load(p, __ATOMIC_RELAXED, __HIP_MEMORY_SCOPE_AGENT);
}
__device__ __forceinline__ float ld_rlx_f(const float* p) {
    return __hip_atomic_load(p, __ATOMIC_RELAXED, __HIP_MEMORY_SCOPE_AGENT);
}
__device__ __forceinline__ void st_rlx_f(float* p, float v) {
    __hip_atomic_store(p, v, __ATOMIC_RELAXED, __HIP_MEMORY_SCOPE_AGENT);
}
__device__ __forceinline__ void st_rlx_u(unsigned* p, unsigned v) {
    __hip_atomic_store(p, v, __ATOMIC_RELAXED, __HIP_MEMORY_SCOPE_AGENT);
}

__global__ __launch_bounds__(BS)
void he_norm_kernel(const float* __restrict__ pic,      // (3,N)
                    const float* __restrict__ Wt,       // (3,4)
                    const float* __restrict__ HtRM,     // scalar
                    const float* __restrict__ W0,       // (N,4)
                    const float* __restrict__ H0,       // (3,4)
                    float* __restrict__ out,            // (3,N)
                    unsigned char* __restrict__ ws)
{
    const int tid  = threadIdx.x;
    const int blk  = blockIdx.x;
    const int g    = blk*BS + tid;
    const int wave = tid >> 6;
    const int lane = tid & 63;
    const int grp  = blk >> 4;            // group id (16 blocks per group)
    const int isLeader = ((blk & 15) == 0);
    const int grpBase  = grp << 4;

    unsigned* U  = (unsigned*)ws;
    float*    F  = (float*)ws;
    unsigned* UG = U + OFF_GLINES;
    float*    FG = F + OFF_GLINES;
    unsigned* gh0 = U + OFF_GH0;
    unsigned* gh1 = U + OFF_GH1;

    __shared__ float sS[22], sWt[12], sScal[2];
    __shared__ float sRed[NWAVE][24];
    __shared__ float sPr[16][22];
    __shared__ unsigned sHist[NBINS];
    __shared__ unsigned sSeg[256];
    __shared__ int      sBstar;
    __shared__ unsigned sCumB;

    // ---- setup: Wt to LDS; Hd, Gram into registers (identical per thread) ----
    if (tid < 12) sWt[tid] = Wt[tid];
    float hd[12], gg[16];
    #pragma unroll
    for (int j = 0; j < 12; j++) hd[j] = H0[j];
    #pragma unroll
    for (int j = 0; j < 16; j++) {
        int s_ = j >> 2, r_ = j & 3;
        gg[j] = hd[s_]*hd[r_] + hd[4+s_]*hd[4+r_] + hd[8+s_]*hd[8+r_];
    }

    // ---- persistent registers: V (optical density) and Wc ----
    float v0[PPT], v1[PPT], v2[PPT];
    float w[PPT][4];
    #pragma unroll
    for (int k = 0; k < PPT; k++) {
        int i = g + k*TT;
        float4 wv = ((const float4*)W0)[i];
        w[k][0]=wv.x; w[k][1]=wv.y; w[k][2]=wv.z; w[k][3]=wv.w;
        v0[k] = -logf(fminf(fmaxf(pic[i],           0.01f), 0.99f));
        v1[k] = -logf(fminf(fmaxf(pic[N_PIX  + i],  0.01f), 0.99f));
        v2[k] = -logf(fminf(fmaxf(pic[2*N_PIX + i], 0.01f), 0.99f));
    }
    __syncthreads();   // sWt ready

    // ---- NMF multiplicative updates ----
    for (int t = 0; t < NIT; ++t) {
        float acc[22];
        #pragma unroll
        for (int j = 0; j < 22; j++) acc[j] = 0.f;

        #pragma unroll
        for (int k = 0; k < PPT; k++) {
            float wn[4];
            #pragma unroll
            for (int r = 0; r < 4; r++) {
                float num = v0[k]*hd[r] + v1[k]*hd[4+r] + v2[k]*hd[8+r];
                float den = w[k][0]*gg[r] + w[k][1]*gg[4+r]
                          + w[k][2]*gg[8+r] + w[k][3]*gg[12+r] + EPSI;
                float rc = __builtin_amdgcn_rcpf(den);
                rc = rc * (2.0f - den*rc);          // 1 NR step: ~exact
                wn[r] = w[k][r] * num * rc;
            }
            #pragma unroll
            for (int r = 0; r < 4; r++) {
                acc[r]    += v0[k]*wn[r];
                acc[4+r]  += v1[k]*wn[r];
                acc[8+r]  += v2[k]*wn[r];
            }
            acc[12]+=wn[0]*wn[0]; acc[13]+=wn[0]*wn[1]; acc[14]+=wn[0]*wn[2]; acc[15]+=wn[0]*wn[3];
            acc[16]+=wn[1]*wn[1]; acc[17]+=wn[1]*wn[2]; acc[18]+=wn[1]*wn[3];
            acc[19]+=wn[2]*wn[2]; acc[20]+=wn[2]*wn[3]; acc[21]+=wn[3]*wn[3];
            w[k][0]=wn[0]; w[k][1]=wn[1]; w[k][2]=wn[2]; w[k][3]=wn[3];
        }

        if (t == NIT-1) break;   // last Hd update is dead code (output uses Wc only)
        const unsigned ep  = (unsigned)(t + 1);
        const int      par = (int)(ep & 1u);

        // ---- block reduce 22 accumulators (wave butterfly -> LDS) ----
        #pragma unroll
        for (int j = 0; j < 22; j++) {
            float v = acc[j];
            #pragma unroll
            for (int off = 32; off > 0; off >>= 1) v += __shfl_down(v, off, 64);
            if (lane == 0) sRed[wave][j] = v;
        }
        __syncthreads();

        // ---- level 1 publish: payload then flag (s_waitcnt-ordered) ----
        if (wave == 0) {
            if (tid < 22) {
                float pa = 0.f;
                #pragma unroll
                for (int wv2 = 0; wv2 < NWAVE; wv2++) pa += sRed[wv2][tid];
                st_rlx_f(&F[(blk*2 + par)*LSTR + tid], pa);
            }
            __builtin_amdgcn_s_waitcnt(0);          // payload acked at coherence point
            if (tid == 0) st_rlx_u(&U[(blk*2 + par)*LSTR + 31], ep);
        }

        // ---- level 2: group leaders fold their 16 block lines ----
        if (isLeader) {
            if (tid < 16) {
                const unsigned* p = &U[((grpBase + tid)*2 + par)*LSTR + 31];
                while (ld_rlx_u(p) < ep) __builtin_amdgcn_s_sleep(1);
            }
            __syncthreads();
            if (tid < 352) {                        // coalesced gather: 16 segs x 22
                int seg = tid / 22, j = tid - seg*22;
                sPr[seg][j] = ld_rlx_f(&F[((grpBase + seg)*2 + par)*LSTR + j]);
            }
            __syncthreads();
            if (wave == 0) {
                if (tid < 22) {
                    float s = 0.f;
                    #pragma unroll
                    for (int sg = 0; sg < 16; sg++) s += sPr[sg][tid];
                    st_rlx_f(&FG[(grp*2 + par)*LSTR + tid], s);
                }
                __builtin_amdgcn_s_waitcnt(0);
                if (tid == 0) st_rlx_u(&UG[(grp*2 + par)*LSTR + 31], ep);
            }
        }

        // ---- all blocks: poll 16 group flags, gather, final fixed-order sum ----
        if (tid < NGRP) {
            const unsigned* p = &UG[(tid*2 + par)*LSTR + 31];
            while (ld_rlx_u(p) < ep) __builtin_amdgcn_s_sleep(1);
        }
        __syncthreads();
        if (tid < 352) {                            // coalesced gather: 16 groups x 22
            int seg = tid / 22, j = tid - seg*22;
            sPr[seg][j] = ld_rlx_f(&FG[(seg*2 + par)*LSTR + j]);
        }
        __syncthreads();
        if (tid < 22) {
            float s = 0.f;
            #pragma unroll
            for (int sg = 0; sg < 16; sg++) s += sPr[sg][tid];
            sS[tid] = s;
        }
        __syncthreads();

        // ---- Hd + Gram update: redundant per-thread, register-only ----
        {
            float nhd[12];
            const int base[4] = {12, 16, 19, 21};
            #pragma unroll
            for (int c = 0; c < 3; c++)
                #pragma unroll
                for (int r = 0; r < 4; r++) {
                    float den = EPSI;
                    #pragma unroll
                    for (int s2 = 0; s2 < 4; s2++) {
                        int lo = (s2 < r) ? s2 : r, hi = (s2 < r) ? r : s2;
                        den += hd[c*4 + s2] * sS[base[lo] + (hi - lo)];
                    }
                    nhd[c*4+r] = hd[c*4+r] * sS[c*4+r] / den;
                }
            #pragma unroll
            for (int j = 0; j < 12; j++) hd[j] = nhd[j];
            #pragma unroll
            for (int j = 0; j < 16; j++) {
                int s_ = j >> 2, r_ = j & 3;
                gg[j] = hd[s_]*hd[r_] + hd[4+s_]*hd[4+r_] + hd[8+s_]*hd[8+r_];
            }
        }
    }

    // ================= tail: quantile + recompose =================
    // ---- ep=100 (par 0): global max of Wc ----
    {
        float m = 0.f;
        #pragma unroll
        for (int k = 0; k < PPT; k++)
            #pragma unroll
            for (int r = 0; r < 4; r++) m = fmaxf(m, w[k][r]);
        #pragma unroll
        for (int off = 32; off > 0; off >>= 1) m = fmaxf(m, __shfl_down(m, off, 64));
        if (lane == 0) sRed[wave][0] = m;
        __syncthreads();
        const unsigned ep = 100u; const int par = 0;
        if (tid == 0) {
            float mm = 0.f;
            for (int wv2 = 0; wv2 < NWAVE; wv2++) mm = fmaxf(mm, sRed[wv2][0]);
            st_rlx_f(&F[(blk*2 + par)*LSTR], mm);
            __builtin_amdgcn_s_waitcnt(0);
            st_rlx_u(&U[(blk*2 + par)*LSTR + 31], ep);
        }
        if (tid < NB) {
            const unsigned* p = &U[(tid*2 + par)*LSTR + 31];
            while (ld_rlx_u(p) < ep) __builtin_amdgcn_s_sleep(1);
        }
        __syncthreads();
        if (tid < NB) {
            float mv = ld_rlx_f(&F[(tid*2 + par)*LSTR]);
            #pragma unroll
            for (int off = 32; off > 0; off >>= 1) mv = fmaxf(mv, __shfl_down(mv, off, 64));
            if (lane == 0) sRed[wave][1] = mv;
        }
        __syncthreads();
        if (tid == 0) {
            float mm = 0.f;
            for (int wv2 = 0; wv2 < 4; wv2++) mm = fmaxf(mm, sRed[wv2][1]);
            sScal[0] = mm * 1.0000002f;
        }
        __syncthreads();
    }
    const float gmax   = sScal[0];
    const float scale0 = (float)NBINS / gmax;

    // ---- ep=101 (par 1): histogram level 0 ----
    for (int i = tid; i < NBINS; i += BS) sHist[i] = 0u;
    __syncthreads();
    #pragma unroll
    for (int k = 0; k < PPT; k++)
        #pragma unroll
        for (int r = 0; r < 4; r++) {
            int b = (int)(w[k][r] * scale0);
            b = min(b, NBINS - 1);
            atomicAdd(&sHist[b], 1u);
        }
    __syncthreads();
    for (int i = tid; i < NBINS; i += BS) if (sHist[i]) atomicAdd(&gh0[i], sHist[i]);
    __builtin_amdgcn_s_waitcnt(0);      // every wave: its hist atomics acked
    __syncthreads();
    if (tid == 0) st_rlx_u(&U[(blk*2 + 1)*LSTR + 31], 101u);
    if (tid < NB) {
        const unsigned* p = &U[(tid*2 + 1)*LSTR + 31];
        while (ld_rlx_u(p) < 101u) __builtin_amdgcn_s_sleep(1);
    }
    __syncthreads();

    // ---- scan level 0 (redundant in every block, exact integer counts) ----
    const double kfd = 0.99 * (double)(4*N_PIX - 1);   // fractional rank
    if (tid < 256) {
        unsigned s2 = 0;
        for (int i = 0; i < 8; i++) s2 += ld_rlx_u(&gh0[tid*8 + i]);
        sSeg[tid] = s2;
    }
    __syncthreads();
    if (tid == 0) {
        unsigned cum = 0; int seg = 0;
        for (int i2 = 0; i2 < 256; i2++) {
            if ((double)(cum + sSeg[i2]) > kfd) { seg = i2; break; }
            cum += sSeg[i2];
        }
        unsigned c2 = cum; int b = seg*8;
        for (int i2 = 0; i2 < 8; i2++) {
            unsigned h = ld_rlx_u(&gh0[seg*8 + i2]);
            if ((double)(c2 + h) > kfd) { b = seg*8 + i2; break; }
            c2 += h;
        }
        sBstar = b; sCumB = c2;
    }
    __syncthreads();
    const int   bstar  = sBstar;
    const float lo1    = (float)bstar / scale0;
    const float scale1 = scale0 * (float)NBINS;

    // ---- ep=102 (par 0): histogram level 1 (values inside bin bstar only) ----
    for (int i = tid; i < NBINS; i += BS) sHist[i] = 0u;
    __syncthreads();
    #pragma unroll
    for (int k = 0; k < PPT; k++)
        #pragma unroll
        for (int r = 0; r < 4; r++) {
            int b0 = min((int)(w[k][r] * scale0), NBINS - 1);
            if (b0 == bstar) {
                int b1 = (int)((w[k][r] - lo1) * scale1);
                b1 = max(0, min(b1, NBINS - 1));
                atomicAdd(&sHist[b1], 1u);
            }
        }
    __syncthreads();
    for (int i = tid; i < NBINS; i += BS) if (sHist[i]) atomicAdd(&gh1[i], sHist[i]);
    __builtin_amdgcn_s_waitcnt(0);
    __syncthreads();
    if (tid == 0) st_rlx_u(&U[(blk*2 + 0)*LSTR + 31], 102u);
    if (tid < NB) {
        const unsigned* p = &U[(tid*2 + 0)*LSTR + 31];
        while (ld_rlx_u(p) < 102u) __builtin_amdgcn_s_sleep(1);
    }
    __syncthreads();

    // ---- scan level 1 -> quantile -> scale factor (redundant) ----
    if (tid < 256) {
        unsigned s2 = 0;
        for (int i = 0; i < 8; i++) s2 += ld_rlx_u(&gh1[tid*8 + i]);
        sSeg[tid] = s2;
    }
    __syncthreads();
    if (tid == 0) {
        double jf = kfd - (double)sCumB;
        unsigned cum = 0; int seg = 0;
        for (int i2 = 0; i2 < 256; i2++) {
            if ((double)(cum + sSeg[i2]) > jf) { seg = i2; break; }
            cum += sSeg[i2];
        }
        unsigned c3 = cum; int bb = seg*8; unsigned hh = 1;
        for (int i2 = 0; i2 < 8; i2++) {
            unsigned h = ld_rlx_u(&gh1[seg*8 + i2]);
            if ((double)(c3 + h) > jf) { bb = seg*8 + i2; hh = h; break; }
            c3 += h;
        }
        double frac = (jf - (double)c3 + 0.5) / (double)hh;
        frac = fmin(fmax(frac, 0.0), 1.0);
        double q = (double)lo1 + ((double)bb + frac) / (double)scale1;
        sScal[1] = (float)((double)HtRM[0] / q);
    }
    __syncthreads();
    const float sc = sScal[1];

    // ---- recompose: out = clip(exp(-(Wt @ (Wc^T * sc))), 0, 1) ----
    #pragma unroll
    for (int k = 0; k < PPT; k++) {
        int i = g + k*TT;
        #pragma unroll
        for (int c = 0; c < 3; c++) {
            float d = sWt[c*4+0]*w[k][0] + sWt[c*4+1]*w[k][1]
                    + sWt[c*4+2]*w[k][2] + sWt[c*4+3]*w[k][3];
            float e = expf(-d * sc);
            out[c*N_PIX + i] = fminf(fmaxf(e, 0.f), 1.f);
        }
    }
}

extern "C" void kernel_launch(void* const* d_in, const int* in_sizes, int n_in,
                              void* d_out, int out_size, void* d_ws, size_t ws_size,
                              hipStream_t stream) {
    const float* pic  = (const float*)d_in[0];
    const float* Wt   = (const float*)d_in[1];
    const float* HtRM = (const float*)d_in[2];
    const float* W0   = (const float*)d_in[3];
    const float* H0   = (const float*)d_in[4];
    float* out = (float*)d_out;

    // zero epoch lines + histograms
    hipMemsetAsync(d_ws, 0, WS_BYTES, stream);
    he_norm_kernel<<<dim3(NB), dim3(BS), 0, stream>>>(
        pic, Wt, HtRM, W0, H0, out, (unsigned char*)d_ws);
}

// Round 7
// 580.407 us; speedup vs baseline: 2.8886x; 1.9907x over previous
//
#include <hip/hip_runtime.h>
#include <math.h>

// HE color normalization: NMF (100 mult-update iters) + 0.99-quantile + recompose.
// Single persistent kernel; V, Wc register-resident; Hd/Gram in LDS.
// R6: epoch-tagged u64 payload words ((ep<<32)|float_bits, relaxed 8B agent
// atomics) make every payload self-validating: publishers fire-and-forget (no
// s_waitcnt ack, no flag), readers fuse detect+gather (spin until tag>=ep, value
// is in the same word). Two-hop topology (16 groups x 16 blocks). Block-level
// 22-accumulator reduction via LDS scatter + tree (replaces shfl butterfly).
// Hd/Gram update computed by wave0 only using in-wave LDS ordering.

#define N_PIX (1024*1024)
#define NB    256            // blocks (1 per CU, co-resident)
#define BS    512            // threads/block (8 waves)
#define NWAVE (BS/64)
#define TT    (NB*BS)
#define PPT   (N_PIX/TT)     // 8 pixels per thread
#define NIT   100
#define EPSI  1e-8f
#define NBINS 2048
#define NGRP  16
#define TSTR  24             // u64 stride per tagged line (192B)

// ---- workspace layout (byte offsets) ----
#define OFF_GH0_B 0
#define OFF_GH1_B 8192
#define OFF_T1_B  16384                          // [NB][2][TSTR] u64
#define OFF_T2_B  (16384 + NB*2*TSTR*8)          // [NGRP][2][TSTR] u64
#define WS_BYTES  (OFF_T2_B + NGRP*2*TSTR*8)

typedef unsigned long long u64;

__device__ __forceinline__ u64 ld_tag(const u64* p) {
    return __hip_atomic_load(p, __ATOMIC_RELAXED, __HIP_MEMORY_SCOPE_AGENT);
}
__device__ __forceinline__ void st_tag(u64* p, u64 v) {
    __hip_atomic_store(p, v, __ATOMIC_RELAXED, __HIP_MEMORY_SCOPE_AGENT);
}
__device__ __forceinline__ unsigned ld_rlx_u(const unsigned* p) {
    return __hip_atomic_load(p, __ATOMIC_RELAXED, __HIP_MEMORY_SCOPE_AGENT);
}
__device__ __forceinline__ u64 pack_tag(unsigned ep, float x) {
    return ((u64)ep << 32) | (u64)__float_as_uint(x);
}
__device__ __forceinline__ float spin_val(const u64* p, unsigned ep) {
    const u64 thr = ((u64)ep) << 32;
    u64 v = ld_tag(p);
    while (v < thr) { __builtin_amdgcn_s_sleep(1); v = ld_tag(p); }
    return __uint_as_float((unsigned)v);
}
__device__ __forceinline__ void spin_only(const u64* p, unsigned ep) {
    const u64 thr = ((u64)ep) << 32;
    while (ld_tag(p) < thr) __builtin_amdgcn_s_sleep(1);
}

__global__ __launch_bounds__(BS)
void he_norm_kernel(const float* __restrict__ pic,      // (3,N)
                    const float* __restrict__ Wt,       // (3,4)
                    const float* __restrict__ HtRM,     // scalar
                    const float* __restrict__ W0,       // (N,4)
                    const float* __restrict__ H0,       // (3,4)
                    float* __restrict__ out,            // (3,N)
                    unsigned char* __restrict__ ws)
{
    const int tid  = threadIdx.x;
    const int blk  = blockIdx.x;
    const int g    = blk*BS + tid;
    const int wave = tid >> 6;
    const int lane = tid & 63;
    const int grp  = blk >> 4;
    const int isLeader = ((blk & 15) == 0);
    const int grpBase  = grp << 4;

    unsigned* gh0 = (unsigned*)(ws + OFF_GH0_B);
    unsigned* gh1 = (unsigned*)(ws + OFF_GH1_B);
    u64*      T1  = (u64*)(ws + OFF_T1_B);
    u64*      T2  = (u64*)(ws + OFF_T2_B);

    __shared__ float sAcc[BS*23];        // 47104 B scatter buffer (reused as scratch)
    __shared__ float sPr[16][22];
    __shared__ float sS[22], sHd[12], sG[16], sWt[12], sScal[2];
    __shared__ float sRed[NWAVE][2];
    __shared__ unsigned sHist[NBINS];
    __shared__ unsigned sSeg[256];
    __shared__ int      sBstar;
    __shared__ unsigned sCumB;

    // ---- setup ----
    if (tid < 12) { sHd[tid] = H0[tid]; sWt[tid] = Wt[tid]; }
    __syncthreads();
    if (tid < 16) {
        int s_ = tid >> 2, r_ = tid & 3;
        sG[tid] = sHd[s_]*sHd[r_] + sHd[4+s_]*sHd[4+r_] + sHd[8+s_]*sHd[8+r_];
    }

    // ---- persistent registers: V (optical density) and Wc ----
    float v0[PPT], v1[PPT], v2[PPT];
    float w[PPT][4];
    #pragma unroll
    for (int k = 0; k < PPT; k++) {
        int i = g + k*TT;
        float4 wv = ((const float4*)W0)[i];
        w[k][0]=wv.x; w[k][1]=wv.y; w[k][2]=wv.z; w[k][3]=wv.w;
        v0[k] = -logf(fminf(fmaxf(pic[i],           0.01f), 0.99f));
        v1[k] = -logf(fminf(fmaxf(pic[N_PIX  + i],  0.01f), 0.99f));
        v2[k] = -logf(fminf(fmaxf(pic[2*N_PIX + i], 0.01f), 0.99f));
    }
    __syncthreads();   // sHd/sG ready

    // ---- NMF multiplicative updates ----
    for (int t = 0; t < NIT; ++t) {
        float hd[12], gg[16];
        #pragma unroll
        for (int j = 0; j < 12; j++) hd[j] = sHd[j];
        #pragma unroll
        for (int j = 0; j < 16; j++) gg[j] = sG[j];

        float acc[22];
        #pragma unroll
        for (int j = 0; j < 22; j++) acc[j] = 0.f;

        #pragma unroll
        for (int k = 0; k < PPT; k++) {
            float wn[4];
            #pragma unroll
            for (int r = 0; r < 4; r++) {
                float num = v0[k]*hd[r] + v1[k]*hd[4+r] + v2[k]*hd[8+r];
                float den = w[k][0]*gg[r] + w[k][1]*gg[4+r]
                          + w[k][2]*gg[8+r] + w[k][3]*gg[12+r] + EPSI;
                float rc = __builtin_amdgcn_rcpf(den);
                rc = rc * (2.0f - den*rc);          // 1 NR step: ~exact
                wn[r] = w[k][r] * num * rc;
            }
            #pragma unroll
            for (int r = 0; r < 4; r++) {
                acc[r]    += v0[k]*wn[r];
                acc[4+r]  += v1[k]*wn[r];
                acc[8+r]  += v2[k]*wn[r];
            }
            acc[12]+=wn[0]*wn[0]; acc[13]+=wn[0]*wn[1]; acc[14]+=wn[0]*wn[2]; acc[15]+=wn[0]*wn[3];
            acc[16]+=wn[1]*wn[1]; acc[17]+=wn[1]*wn[2]; acc[18]+=wn[1]*wn[3];
            acc[19]+=wn[2]*wn[2]; acc[20]+=wn[2]*wn[3]; acc[21]+=wn[3]*wn[3];
            w[k][0]=wn[0]; w[k][1]=wn[1]; w[k][2]=wn[2]; w[k][3]=wn[3];
        }

        if (t == NIT-1) break;   // last Hd update is dead code (output uses Wc only)
        const unsigned ep  = (unsigned)(t + 1);
        const int      par = (int)(ep & 1u);

        // ---- block reduce: LDS scatter (stride 23, 2-way = free) + tree ----
        #pragma unroll
        for (int j = 0; j < 22; j++) sAcc[tid*23 + j] = acc[j];
        __syncthreads();                                        // B1
        if (tid < 352) {
            int seg = tid / 22, j = tid - seg*22;
            const float* row = &sAcc[(seg*32)*23 + j];
            float p0=0.f, p1=0.f, p2=0.f, p3=0.f;
            #pragma unroll
            for (int b = 0; b < 32; b += 4) {
                p0 += row[(b+0)*23]; p1 += row[(b+1)*23];
                p2 += row[(b+2)*23]; p3 += row[(b+3)*23];
            }
            sPr[seg][j] = (p0+p1)+(p2+p3);
        }
        __syncthreads();                                        // B2
        if (tid < 22) {                    // block partial -> tagged publish
            float bp = 0.f;
            #pragma unroll
            for (int sg = 0; sg < 16; sg++) bp += sPr[sg][tid];
            st_tag(&T1[(blk*2 + par)*TSTR + tid], pack_tag(ep, bp));
        }
        __syncthreads();                                        // B3 (sPr reuse)

        // ---- level 2: leaders fold member words (fused detect+gather) ----
        if (isLeader) {
            if (tid < 352) {
                int m = tid / 22, j = tid - m*22;
                sPr[m][j] = spin_val(&T1[((grpBase + m)*2 + par)*TSTR + j], ep);
            }
            __syncthreads();                                    // B4L
            if (tid < 22) {
                float gp = 0.f;
                #pragma unroll
                for (int m = 0; m < 16; m++) gp += sPr[m][tid];
                st_tag(&T2[(grp*2 + par)*TSTR + tid], pack_tag(ep, gp));
            }
            __syncthreads();                                    // B5L (sPr reuse)
        }

        // ---- all blocks: fused detect+gather of 16 group words ----
        if (tid < 352) {
            int g2 = tid / 22, j = tid - g2*22;
            sPr[g2][j] = spin_val(&T2[(g2*2 + par)*TSTR + j], ep);
        }
        __syncthreads();                                        // B6
        if (tid < 22) {
            float s = 0.f;
            #pragma unroll
            for (int g2 = 0; g2 < 16; g2++) s += sPr[g2][tid];
            sS[tid] = s;
        }
        __syncthreads();                                        // B7

        // ---- Hd + Gram update: wave0 only, in-wave LDS ordering ----
        if (wave == 0) {
            if (lane < 12) {
                int c = lane >> 2, r = lane & 3;
                const int base[4] = {12, 16, 19, 21};
                float den = EPSI;
                #pragma unroll
                for (int s2 = 0; s2 < 4; s2++) {
                    int lo = (s2 < r) ? s2 : r, hi = (s2 < r) ? r : s2;
                    den += sHd[c*4 + s2] * sS[base[lo] + (hi - lo)];
                }
                float nhd = sHd[lane] * sS[lane] / den;
                sHd[lane] = nhd;            // reads (above) precede write in wave
            }
            if (lane < 16) {                // reads new sHd, in-wave ordered
                int s_ = lane >> 2, r_ = lane & 3;
                sG[lane] = sHd[s_]*sHd[r_] + sHd[4+s_]*sHd[4+r_] + sHd[8+s_]*sHd[8+r_];
            }
        }
        __syncthreads();                                        // B8
    }

    // ================= tail: quantile + recompose =================
    // ---- ep=100 (par 0, word 0): global max of Wc ----
    {
        float m = 0.f;
        #pragma unroll
        for (int k = 0; k < PPT; k++)
            #pragma unroll
            for (int r = 0; r < 4; r++) m = fmaxf(m, w[k][r]);
        #pragma unroll
        for (int off = 32; off > 0; off >>= 1) m = fmaxf(m, __shfl_down(m, off, 64));
        if (lane == 0) sRed[wave][0] = m;
        __syncthreads();
        if (tid == 0) {
            float mm = 0.f;
            for (int wv2 = 0; wv2 < NWAVE; wv2++) mm = fmaxf(mm, sRed[wv2][0]);
            st_tag(&T1[(blk*2 + 0)*TSTR + 0], pack_tag(100u, mm));
        }
        if (tid < NB) sAcc[tid] = spin_val(&T1[(tid*2 + 0)*TSTR + 0], 100u);
        __syncthreads();
        if (tid < NB) {
            float mv = sAcc[tid];
            #pragma unroll
            for (int off = 32; off > 0; off >>= 1) mv = fmaxf(mv, __shfl_down(mv, off, 64));
            if (lane == 0) sRed[wave][1] = mv;
        }
        __syncthreads();
        if (tid == 0) {
            float mm = 0.f;
            for (int wv2 = 0; wv2 < 4; wv2++) mm = fmaxf(mm, sRed[wv2][1]);
            sScal[0] = mm * 1.0000002f;
        }
        __syncthreads();
    }
    const float gmax   = sScal[0];
    const float scale0 = (float)NBINS / gmax;

    // ---- ep=101 (par 1, word 0): histogram level 0 ----
    for (int i = tid; i < NBINS; i += BS) sHist[i] = 0u;
    __syncthreads();
    #pragma unroll
    for (int k = 0; k < PPT; k++)
        #pragma unroll
        for (int r = 0; r < 4; r++) {
            int b = (int)(w[k][r] * scale0);
            b = min(b, NBINS - 1);
            atomicAdd(&sHist[b], 1u);
        }
    __syncthreads();
    for (int i = tid; i < NBINS; i += BS) if (sHist[i]) atomicAdd(&gh0[i], sHist[i]);
    __builtin_amdgcn_s_waitcnt(0);      // every wave: its hist atomics acked
    __syncthreads();
    if (tid == 0) st_tag(&T1[(blk*2 + 1)*TSTR + 0], pack_tag(101u, 0.f));
    if (tid < NB) spin_only(&T1[(tid*2 + 1)*TSTR + 0], 101u);
    __syncthreads();

    // ---- scan level 0 (redundant in every block, exact integer counts) ----
    const double kfd = 0.99 * (double)(4*N_PIX - 1);   // fractional rank
    if (tid < 256) {
        unsigned s2 = 0;
        for (int i = 0; i < 8; i++) s2 += ld_rlx_u(&gh0[tid*8 + i]);
        sSeg[tid] = s2;
    }
    __syncthreads();
    if (tid == 0) {
        unsigned cum = 0; int seg = 0;
        for (int i2 = 0; i2 < 256; i2++) {
            if ((double)(cum + sSeg[i2]) > kfd) { seg = i2; break; }
            cum += sSeg[i2];
        }
        unsigned c2 = cum; int b = seg*8;
        for (int i2 = 0; i2 < 8; i2++) {
            unsigned h = ld_rlx_u(&gh0[seg*8 + i2]);
            if ((double)(c2 + h) > kfd) { b = seg*8 + i2; break; }
            c2 += h;
        }
        sBstar = b; sCumB = c2;
    }
    __syncthreads();
    const int   bstar  = sBstar;
    const float lo1    = (float)bstar / scale0;
    const float scale1 = scale0 * (float)NBINS;

    // ---- ep=102 (par 0, word 0): histogram level 1 ----
    for (int i = tid; i < NBINS; i += BS) sHist[i] = 0u;
    __syncthreads();
    #pragma unroll
    for (int k = 0; k < PPT; k++)
        #pragma unroll
        for (int r = 0; r < 4; r++) {
            int b0 = min((int)(w[k][r] * scale0), NBINS - 1);
            if (b0 == bstar) {
                int b1 = (int)((w[k][r] - lo1) * scale1);
                b1 = max(0, min(b1, NBINS - 1));
                atomicAdd(&sHist[b1], 1u);
            }
        }
    __syncthreads();
    for (int i = tid; i < NBINS; i += BS) if (sHist[i]) atomicAdd(&gh1[i], sHist[i]);
    __builtin_amdgcn_s_waitcnt(0);
    __syncthreads();
    if (tid == 0) st_tag(&T1[(blk*2 + 0)*TSTR + 0], pack_tag(102u, 0.f));
    if (tid < NB) spin_only(&T1[(tid*2 + 0)*TSTR + 0], 102u);
    __syncthreads();

    // ---- scan level 1 -> quantile -> scale factor (redundant) ----
    if (tid < 256) {
        unsigned s2 = 0;
        for (int i = 0; i < 8; i++) s2 += ld_rlx_u(&gh1[tid*8 + i]);
        sSeg[tid] = s2;
    }
    __syncthreads();
    if (tid == 0) {
        double jf = kfd - (double)sCumB;
        unsigned cum = 0; int seg = 0;
        for (int i2 = 0; i2 < 256; i2++) {
            if ((double)(cum + sSeg[i2]) > jf) { seg = i2; break; }
            cum += sSeg[i2];
        }
        unsigned c3 = cum; int bb = seg*8; unsigned hh = 1;
        for (int i2 = 0; i2 < 8; i2++) {
            unsigned h = ld_rlx_u(&gh1[seg*8 + i2]);
            if ((double)(c3 + h) > jf) { bb = seg*8 + i2; hh = h; break; }
            c3 += h;
        }
        double frac = (jf - (double)c3 + 0.5) / (double)hh;
        frac = fmin(fmax(frac, 0.0), 1.0);
        double q = (double)lo1 + ((double)bb + frac) / (double)scale1;
        sScal[1] = (float)((double)HtRM[0] / q);
    }
    __syncthreads();
    const float sc = sScal[1];

    // ---- recompose: out = clip(exp(-(Wt @ (Wc^T * sc))), 0, 1) ----
    #pragma unroll
    for (int k = 0; k < PPT; k++) {
        int i = g + k*TT;
        #pragma unroll
        for (int c = 0; c < 3; c++) {
            float d = sWt[c*4+0]*w[k][0] + sWt[c*4+1]*w[k][1]
                    + sWt[c*4+2]*w[k][2] + sWt[c*4+3]*w[k][3];
            float e = expf(-d * sc);
            out[c*N_PIX + i] = fminf(fmaxf(e, 0.f), 1.f);
        }
    }
}

extern "C" void kernel_launch(void* const* d_in, const int* in_sizes, int n_in,
                              void* d_out, int out_size, void* d_ws, size_t ws_size,
                              hipStream_t stream) {
    const float* pic  = (const float*)d_in[0];
    const float* Wt   = (const float*)d_in[1];
    const float* HtRM = (const float*)d_in[2];
    const float* W0   = (const float*)d_in[3];
    const float* H0   = (const float*)d_in[4];
    float* out = (float*)d_out;

    // zero histograms + tagged-word regions (tags start at epoch 0)
    hipMemsetAsync(d_ws, 0, WS_BYTES, stream);
    he_norm_kernel<<<dim3(NB), dim3(BS), 0, stream>>>(
        pic, Wt, HtRM, W0, H0, out, (unsigned char*)d_ws);
}

// Round 8
// 572.674 us; speedup vs baseline: 2.9276x; 1.0135x over previous
//
#include <hip/hip_runtime.h>
#include <math.h>

// HE color normalization: NMF (100 mult-update iters) + 0.99-quantile + recompose.
// Single persistent kernel; V, Wc register-resident; Hd/Gram in LDS.
// R7 = R6 (epoch-tagged fire-and-forget u64 words, two-hop 16x16 topology)
// + 16x-replicated group words: leaders publish group sums to 16 replica sets;
// block b polls/gathers replica (b&15) only -> 16 readers per line instead of
// 256, removing the broadcast hot-bank serialization at the coherence point.

#define N_PIX (1024*1024)
#define NB    256            // blocks (1 per CU, co-resident)
#define BS    512            // threads/block (8 waves)
#define NWAVE (BS/64)
#define TT    (NB*BS)
#define PPT   (N_PIX/TT)     // 8 pixels per thread
#define NIT   100
#define EPSI  1e-8f
#define NBINS 2048
#define NGRP  16
#define NREP  16
#define TSTR  24             // u64 stride per tagged line (192B)

// ---- workspace layout (byte offsets) ----
#define OFF_GH0_B 0
#define OFF_GH1_B 8192
#define OFF_T1_B  16384                          // [NB][2][TSTR] u64
#define OFF_T2_B  (16384 + NB*2*TSTR*8)          // [2][NREP][NGRP][TSTR] u64
#define WS_BYTES  (OFF_T2_B + 2*NREP*NGRP*TSTR*8)

typedef unsigned long long u64;

__device__ __forceinline__ u64 ld_tag(const u64* p) {
    return __hip_atomic_load(p, __ATOMIC_RELAXED, __HIP_MEMORY_SCOPE_AGENT);
}
__device__ __forceinline__ void st_tag(u64* p, u64 v) {
    __hip_atomic_store(p, v, __ATOMIC_RELAXED, __HIP_MEMORY_SCOPE_AGENT);
}
__device__ __forceinline__ unsigned ld_rlx_u(const unsigned* p) {
    return __hip_atomic_load(p, __ATOMIC_RELAXED, __HIP_MEMORY_SCOPE_AGENT);
}
__device__ __forceinline__ u64 pack_tag(unsigned ep, float x) {
    return ((u64)ep << 32) | (u64)__float_as_uint(x);
}
__device__ __forceinline__ float spin_val(const u64* p, unsigned ep) {
    const u64 thr = ((u64)ep) << 32;
    u64 v = ld_tag(p);
    while (v < thr) { __builtin_amdgcn_s_sleep(1); v = ld_tag(p); }
    return __uint_as_float((unsigned)v);
}
__device__ __forceinline__ void spin_only(const u64* p, unsigned ep) {
    const u64 thr = ((u64)ep) << 32;
    while (ld_tag(p) < thr) __builtin_amdgcn_s_sleep(1);
}

__global__ __launch_bounds__(BS)
void he_norm_kernel(const float* __restrict__ pic,      // (3,N)
                    const float* __restrict__ Wt,       // (3,4)
                    const float* __restrict__ HtRM,     // scalar
                    const float* __restrict__ W0,       // (N,4)
                    const float* __restrict__ H0,       // (3,4)
                    float* __restrict__ out,            // (3,N)
                    unsigned char* __restrict__ ws)
{
    const int tid  = threadIdx.x;
    const int blk  = blockIdx.x;
    const int g    = blk*BS + tid;
    const int wave = tid >> 6;
    const int lane = tid & 63;
    const int grp  = blk >> 4;
    const int rep  = blk & 15;            // replica set this block reads
    const int isLeader = ((blk & 15) == 0);
    const int grpBase  = grp << 4;

    unsigned* gh0 = (unsigned*)(ws + OFF_GH0_B);
    unsigned* gh1 = (unsigned*)(ws + OFF_GH1_B);
    u64*      T1  = (u64*)(ws + OFF_T1_B);
    u64*      T2  = (u64*)(ws + OFF_T2_B);

    __shared__ float sAcc[BS*23];        // 47104 B scatter buffer (reused as scratch)
    __shared__ float sPr[16][22];
    __shared__ float sS[22], sHd[12], sG[16], sWt[12], sScal[2];
    __shared__ float sRed[NWAVE][2];
    __shared__ unsigned sHist[NBINS];
    __shared__ unsigned sSeg[256];
    __shared__ int      sBstar;
    __shared__ unsigned sCumB;

    // ---- setup ----
    if (tid < 12) { sHd[tid] = H0[tid]; sWt[tid] = Wt[tid]; }
    __syncthreads();
    if (tid < 16) {
        int s_ = tid >> 2, r_ = tid & 3;
        sG[tid] = sHd[s_]*sHd[r_] + sHd[4+s_]*sHd[4+r_] + sHd[8+s_]*sHd[8+r_];
    }

    // ---- persistent registers: V (optical density) and Wc ----
    float v0[PPT], v1[PPT], v2[PPT];
    float w[PPT][4];
    #pragma unroll
    for (int k = 0; k < PPT; k++) {
        int i = g + k*TT;
        float4 wv = ((const float4*)W0)[i];
        w[k][0]=wv.x; w[k][1]=wv.y; w[k][2]=wv.z; w[k][3]=wv.w;
        v0[k] = -logf(fminf(fmaxf(pic[i],           0.01f), 0.99f));
        v1[k] = -logf(fminf(fmaxf(pic[N_PIX  + i],  0.01f), 0.99f));
        v2[k] = -logf(fminf(fmaxf(pic[2*N_PIX + i], 0.01f), 0.99f));
    }
    __syncthreads();   // sHd/sG ready

    // ---- NMF multiplicative updates ----
    for (int t = 0; t < NIT; ++t) {
        float hd[12], gg[16];
        #pragma unroll
        for (int j = 0; j < 12; j++) hd[j] = sHd[j];
        #pragma unroll
        for (int j = 0; j < 16; j++) gg[j] = sG[j];

        float acc[22];
        #pragma unroll
        for (int j = 0; j < 22; j++) acc[j] = 0.f;

        #pragma unroll
        for (int k = 0; k < PPT; k++) {
            float wn[4];
            #pragma unroll
            for (int r = 0; r < 4; r++) {
                float num = v0[k]*hd[r] + v1[k]*hd[4+r] + v2[k]*hd[8+r];
                float den = w[k][0]*gg[r] + w[k][1]*gg[4+r]
                          + w[k][2]*gg[8+r] + w[k][3]*gg[12+r] + EPSI;
                float rc = __builtin_amdgcn_rcpf(den);
                rc = rc * (2.0f - den*rc);          // 1 NR step: ~exact
                wn[r] = w[k][r] * num * rc;
            }
            #pragma unroll
            for (int r = 0; r < 4; r++) {
                acc[r]    += v0[k]*wn[r];
                acc[4+r]  += v1[k]*wn[r];
                acc[8+r]  += v2[k]*wn[r];
            }
            acc[12]+=wn[0]*wn[0]; acc[13]+=wn[0]*wn[1]; acc[14]+=wn[0]*wn[2]; acc[15]+=wn[0]*wn[3];
            acc[16]+=wn[1]*wn[1]; acc[17]+=wn[1]*wn[2]; acc[18]+=wn[1]*wn[3];
            acc[19]+=wn[2]*wn[2]; acc[20]+=wn[2]*wn[3]; acc[21]+=wn[3]*wn[3];
            w[k][0]=wn[0]; w[k][1]=wn[1]; w[k][2]=wn[2]; w[k][3]=wn[3];
        }

        if (t == NIT-1) break;   // last Hd update is dead code (output uses Wc only)
        const unsigned ep  = (unsigned)(t + 1);
        const int      par = (int)(ep & 1u);

        // ---- block reduce: LDS scatter (stride 23, 2-way = free) + tree ----
        #pragma unroll
        for (int j = 0; j < 22; j++) sAcc[tid*23 + j] = acc[j];
        __syncthreads();                                        // B1
        if (tid < 352) {
            int seg = tid / 22, j = tid - seg*22;
            const float* row = &sAcc[(seg*32)*23 + j];
            float p0=0.f, p1=0.f, p2=0.f, p3=0.f;
            #pragma unroll
            for (int b = 0; b < 32; b += 4) {
                p0 += row[(b+0)*23]; p1 += row[(b+1)*23];
                p2 += row[(b+2)*23]; p3 += row[(b+3)*23];
            }
            sPr[seg][j] = (p0+p1)+(p2+p3);
        }
        __syncthreads();                                        // B2
        if (tid < 22) {                    // block partial -> tagged publish
            float bp = 0.f;
            #pragma unroll
            for (int sg = 0; sg < 16; sg++) bp += sPr[sg][tid];
            st_tag(&T1[(blk*2 + par)*TSTR + tid], pack_tag(ep, bp));
        }
        __syncthreads();                                        // B3 (sPr reuse)

        // ---- level 2: leaders fold member words, publish 16 replicas ----
        if (isLeader) {
            if (tid < 352) {
                int m = tid / 22, j = tid - m*22;
                sPr[m][j] = spin_val(&T1[((grpBase + m)*2 + par)*TSTR + j], ep);
            }
            __syncthreads();                                    // B4L
            if (tid < 22) {
                float gp = 0.f;
                #pragma unroll
                for (int m = 0; m < 16; m++) gp += sPr[m][tid];
                const u64 word = pack_tag(ep, gp);
                #pragma unroll
                for (int r2 = 0; r2 < NREP; r2++)   // fire-and-forget replicas
                    st_tag(&T2[((par*NREP + r2)*NGRP + grp)*TSTR + tid], word);
            }
            __syncthreads();                                    // B5L (sPr reuse)
        }

        // ---- all blocks: fused detect+gather from own replica set ----
        if (tid < 352) {
            int g2 = tid / 22, j = tid - g2*22;
            sPr[g2][j] = spin_val(&T2[((par*NREP + rep)*NGRP + g2)*TSTR + j], ep);
        }
        __syncthreads();                                        // B6
        if (tid < 22) {
            float s = 0.f;
            #pragma unroll
            for (int g2 = 0; g2 < 16; g2++) s += sPr[g2][tid];
            sS[tid] = s;
        }
        __syncthreads();                                        // B7

        // ---- Hd + Gram update: wave0 only, in-wave LDS ordering ----
        if (wave == 0) {
            if (lane < 12) {
                int c = lane >> 2, r = lane & 3;
                const int base[4] = {12, 16, 19, 21};
                float den = EPSI;
                #pragma unroll
                for (int s2 = 0; s2 < 4; s2++) {
                    int lo = (s2 < r) ? s2 : r, hi = (s2 < r) ? r : s2;
                    den += sHd[c*4 + s2] * sS[base[lo] + (hi - lo)];
                }
                float nhd = sHd[lane] * sS[lane] / den;
                sHd[lane] = nhd;            // reads (above) precede write in wave
            }
            if (lane < 16) {                // reads new sHd, in-wave ordered
                int s_ = lane >> 2, r_ = lane & 3;
                sG[lane] = sHd[s_]*sHd[r_] + sHd[4+s_]*sHd[4+r_] + sHd[8+s_]*sHd[8+r_];
            }
        }
        __syncthreads();                                        // B8
    }

    // ================= tail: quantile + recompose =================
    // ---- ep=100 (par 0, word 0): global max of Wc ----
    {
        float m = 0.f;
        #pragma unroll
        for (int k = 0; k < PPT; k++)
            #pragma unroll
            for (int r = 0; r < 4; r++) m = fmaxf(m, w[k][r]);
        #pragma unroll
        for (int off = 32; off > 0; off >>= 1) m = fmaxf(m, __shfl_down(m, off, 64));
        if (lane == 0) sRed[wave][0] = m;
        __syncthreads();
        if (tid == 0) {
            float mm = 0.f;
            for (int wv2 = 0; wv2 < NWAVE; wv2++) mm = fmaxf(mm, sRed[wv2][0]);
            st_tag(&T1[(blk*2 + 0)*TSTR + 0], pack_tag(100u, mm));
        }
        if (tid < NB) sAcc[tid] = spin_val(&T1[(tid*2 + 0)*TSTR + 0], 100u);
        __syncthreads();
        if (tid < NB) {
            float mv = sAcc[tid];
            #pragma unroll
            for (int off = 32; off > 0; off >>= 1) mv = fmaxf(mv, __shfl_down(mv, off, 64));
            if (lane == 0) sRed[wave][1] = mv;
        }
        __syncthreads();
        if (tid == 0) {
            float mm = 0.f;
            for (int wv2 = 0; wv2 < 4; wv2++) mm = fmaxf(mm, sRed[wv2][1]);
            sScal[0] = mm * 1.0000002f;
        }
        __syncthreads();
    }
    const float gmax   = sScal[0];
    const float scale0 = (float)NBINS / gmax;

    // ---- ep=101 (par 1, word 0): histogram level 0 ----
    for (int i = tid; i < NBINS; i += BS) sHist[i] = 0u;
    __syncthreads();
    #pragma unroll
    for (int k = 0; k < PPT; k++)
        #pragma unroll
        for (int r = 0; r < 4; r++) {
            int b = (int)(w[k][r] * scale0);
            b = min(b, NBINS - 1);
            atomicAdd(&sHist[b], 1u);
        }
    __syncthreads();
    for (int i = tid; i < NBINS; i += BS) if (sHist[i]) atomicAdd(&gh0[i], sHist[i]);
    __builtin_amdgcn_s_waitcnt(0);      // every wave: its hist atomics acked
    __syncthreads();
    if (tid == 0) st_tag(&T1[(blk*2 + 1)*TSTR + 0], pack_tag(101u, 0.f));
    if (tid < NB) spin_only(&T1[(tid*2 + 1)*TSTR + 0], 101u);
    __syncthreads();

    // ---- scan level 0 (redundant in every block, exact integer counts) ----
    const double kfd = 0.99 * (double)(4*N_PIX - 1);   // fractional rank
    if (tid < 256) {
        unsigned s2 = 0;
        for (int i = 0; i < 8; i++) s2 += ld_rlx_u(&gh0[tid*8 + i]);
        sSeg[tid] = s2;
    }
    __syncthreads();
    if (tid == 0) {
        unsigned cum = 0; int seg = 0;
        for (int i2 = 0; i2 < 256; i2++) {
            if ((double)(cum + sSeg[i2]) > kfd) { seg = i2; break; }
            cum += sSeg[i2];
        }
        unsigned c2 = cum; int b = seg*8;
        for (int i2 = 0; i2 < 8; i2++) {
            unsigned h = ld_rlx_u(&gh0[seg*8 + i2]);
            if ((double)(c2 + h) > kfd) { b = seg*8 + i2; break; }
            c2 += h;
        }
        sBstar = b; sCumB = c2;
    }
    __syncthreads();
    const int   bstar  = sBstar;
    const float lo1    = (float)bstar / scale0;
    const float scale1 = scale0 * (float)NBINS;

    // ---- ep=102 (par 0, word 0): histogram level 1 ----
    for (int i = tid; i < NBINS; i += BS) sHist[i] = 0u;
    __syncthreads();
    #pragma unroll
    for (int k = 0; k < PPT; k++)
        #pragma unroll
        for (int r = 0; r < 4; r++) {
            int b0 = min((int)(w[k][r] * scale0), NBINS - 1);
            if (b0 == bstar) {
                int b1 = (int)((w[k][r] - lo1) * scale1);
                b1 = max(0, min(b1, NBINS - 1));
                atomicAdd(&sHist[b1], 1u);
            }
        }
    __syncthreads();
    for (int i = tid; i < NBINS; i += BS) if (sHist[i]) atomicAdd(&gh1[i], sHist[i]);
    __builtin_amdgcn_s_waitcnt(0);
    __syncthreads();
    if (tid == 0) st_tag(&T1[(blk*2 + 0)*TSTR + 0], pack_tag(102u, 0.f));
    if (tid < NB) spin_only(&T1[(tid*2 + 0)*TSTR + 0], 102u);
    __syncthreads();

    // ---- scan level 1 -> quantile -> scale factor (redundant) ----
    if (tid < 256) {
        unsigned s2 = 0;
        for (int i = 0; i < 8; i++) s2 += ld_rlx_u(&gh1[tid*8 + i]);
        sSeg[tid] = s2;
    }
    __syncthreads();
    if (tid == 0) {
        double jf = kfd - (double)sCumB;
        unsigned cum = 0; int seg = 0;
        for (int i2 = 0; i2 < 256; i2++) {
            if ((double)(cum + sSeg[i2]) > jf) { seg = i2; break; }
            cum += sSeg[i2];
        }
        unsigned c3 = cum; int bb = seg*8; unsigned hh = 1;
        for (int i2 = 0; i2 < 8; i2++) {
            unsigned h = ld_rlx_u(&gh1[seg*8 + i2]);
            if ((double)(c3 + h) > jf) { bb = seg*8 + i2; hh = h; break; }
            c3 += h;
        }
        double frac = (jf - (double)c3 + 0.5) / (double)hh;
        frac = fmin(fmax(frac, 0.0), 1.0);
        double q = (double)lo1 + ((double)bb + frac) / (double)scale1;
        sScal[1] = (float)((double)HtRM[0] / q);
    }
    __syncthreads();
    const float sc = sScal[1];

    // ---- recompose: out = clip(exp(-(Wt @ (Wc^T * sc))), 0, 1) ----
    #pragma unroll
    for (int k = 0; k < PPT; k++) {
        int i = g + k*TT;
        #pragma unroll
        for (int c = 0; c < 3; c++) {
            float d = sWt[c*4+0]*w[k][0] + sWt[c*4+1]*w[k][1]
                    + sWt[c*4+2]*w[k][2] + sWt[c*4+3]*w[k][3];
            float e = expf(-d * sc);
            out[c*N_PIX + i] = fminf(fmaxf(e, 0.f), 1.f);
        }
    }
}

extern "C" void kernel_launch(void* const* d_in, const int* in_sizes, int n_in,
                              void* d_out, int out_size, void* d_ws, size_t ws_size,
                              hipStream_t stream) {
    const float* pic  = (const float*)d_in[0];
    const float* Wt   = (const float*)d_in[1];
    const float* HtRM = (const float*)d_in[2];
    const float* W0   = (const float*)d_in[3];
    const float* H0   = (const float*)d_in[4];
    float* out = (float*)d_out;

    // zero histograms + tagged-word regions (tags start at epoch 0)
    hipMemsetAsync(d_ws, 0, WS_BYTES, stream);
    he_norm_kernel<<<dim3(NB), dim3(BS), 0, stream>>>(
        pic, Wt, HtRM, W0, H0, out, (unsigned char*)d_ws);
}